// Round 8
// baseline (1290.180 us; speedup 1.0000x reference)
//
#include <hip/hip_runtime.h>
#include <cstdint>
#include <math.h>

typedef short bf16x8 __attribute__((ext_vector_type(8)));
typedef float f32x4 __attribute__((ext_vector_type(4)));

__device__ __forceinline__ unsigned short f2bf(float x) {
  union { float f; uint32_t u; } v; v.f = x;
  return (unsigned short)((v.u + 0x7FFFu + ((v.u >> 16) & 1u)) >> 16);
}
__device__ __forceinline__ float bf2f(unsigned short h) {
  union { uint32_t u; float f; } v; v.u = ((uint32_t)h) << 16;
  return v.f;
}

// async global->LDS, 16B per lane (global_load_lds_dwordx4). LDS dest is
// wave-uniform base; HW writes base + lane*16.
__device__ __forceinline__ void ld_lds16(const unsigned short* g, unsigned short* l) {
  auto gp = (const __attribute__((address_space(1))) unsigned short*)(uintptr_t)g;
  auto lp = (__attribute__((address_space(3))) unsigned short*)(uint32_t)(uintptr_t)l;
  __builtin_amdgcn_global_load_lds(gp, lp, 16, 0, 0);
}

// 32-col tiles (64B rows = 4 chunks of 16B): XOR-swizzle chunk with (row>>1)&3.
// DMA writes LDS linearly, so the swizzle is applied to the per-lane GLOBAL
// source column; read applies the same XOR -> 2-way max bank conflicts.
#define DMA_COL(lane) ((((lane) & 3) ^ (((lane) >> 3) & 3)) * 8)
#define SWZ(l15) ((((l15) >> 1) & 3) * 8)

// split fp32 -> bf16 hi + bf16 lo (residual)
__global__ __launch_bounds__(256) void split_f32(const float* __restrict__ src,
                                                 unsigned short* __restrict__ hi,
                                                 unsigned short* __restrict__ lo, int n) {
  int i = (blockIdx.x * 256 + threadIdx.x) * 4;
  if (i >= n) return;
  float4 v = *(const float4*)(src + i);
  ushort4 h, l;
  h.x = f2bf(v.x); l.x = f2bf(v.x - bf2f(h.x));
  h.y = f2bf(v.y); l.y = f2bf(v.y - bf2f(h.y));
  h.z = f2bf(v.z); l.z = f2bf(v.z - bf2f(h.z));
  h.w = f2bf(v.w); l.w = f2bf(v.w - bf2f(h.w));
  *(ushort4*)(hi + i) = h;
  *(ushort4*)(lo + i) = l;
}

// transpose W (K x N) -> hiT/loT (N x K) bf16
template<bool LO>
__global__ __launch_bounds__(256) void tsplit(const float* __restrict__ W,
                                              unsigned short* __restrict__ hiT,
                                              unsigned short* __restrict__ loT,
                                              int K, int N) {
  __shared__ float tile[32][33];
  const int tx = threadIdx.x, ty = threadIdx.y;  // 32 x 8
  const int bx = blockIdx.x, by = blockIdx.y;
#pragma unroll
  for (int i = 0; i < 4; ++i)
    tile[ty + i * 8][tx] = W[(size_t)(by * 32 + ty + i * 8) * N + bx * 32 + tx];
  __syncthreads();
#pragma unroll
  for (int i = 0; i < 4; ++i) {
    float v = tile[tx][ty + i * 8];
    size_t o = (size_t)(bx * 32 + ty + i * 8) * K + by * 32 + tx;
    unsigned short h = f2bf(v);
    hiT[o] = h;
    if (LO) loT[o] = f2bf(v - bf2f(h));
  }
}

// Fused Q/K/V projection v4: ONE block computes Q, K AND V 256x128 tiles.
// X (hi/lo) is staged ONCE per K-step and feeds all three products:
// 72KB/step -> 896 MFMAs/step (Q 48 + K 48 + V 16 per wave x 8 waves),
// vs v3's 64KB/768 + a separate low-intensity V round.
// 2 LDS buffers x 72KB, depth-1 prefetch (stage split: 5 chunks at step
// start, 4 after the Q cluster to spread DMA off the read-heavy phase),
// vmcnt(0)+barrier per step. setprio around MFMA clusters; sched_barrier
// between clusters bounds register pressure (3 accumulators live).
// Grid (16, C*8) = 256 blocks = one CU round; XCD-contiguous swizzle
// (identical-duration blocks -> balanced by construction).
__global__ __launch_bounds__(512, 2) void gemm_qkv4(
    const unsigned short* __restrict__ Xhi, const unsigned short* __restrict__ Xlo,
    const unsigned short* __restrict__ Wq_h, const unsigned short* __restrict__ Wq_l,
    const unsigned short* __restrict__ Wk_h, const unsigned short* __restrict__ Wk_l,
    const unsigned short* __restrict__ Wv_h,
    unsigned short* __restrict__ Qhi, unsigned short* __restrict__ Qlo,
    unsigned short* __restrict__ Khi, unsigned short* __restrict__ Klo,
    unsigned short* __restrict__ Vt, float qscale) {
  __shared__ unsigned short sm[2 * 36864];  // 144 KiB
  const int K = 2048, N = 2048;
  // XCD-contiguous swizzle (bijective: gx*gy divisible by 8)
  const int gx = gridDim.x, gy = gridDim.y;
  const int lid = blockIdx.x + gx * blockIdx.y;
  const int wiz = (lid & 7) * ((gx * gy) >> 3) + (lid >> 3);
  const int bx = wiz % gx;
  const int by = wiz / gx;
  const int t = threadIdx.x;
  const int wave = t >> 6, lane = t & 63, quad = lane >> 4, l15 = lane & 15;
  const int m0 = by * 256, n0 = bx * 128;
  const int wm = (wave >> 1) * 64, wn = (wave & 1) * 64;
  const int cq0 = (quad * 8) ^ SWZ(l15);

  // 72 wave-load chunks/step (Xhi 16, Xlo 16, Wqh 8, Wql 8, Wkh 8, Wkl 8,
  // Wvh 8) -> 9 per wave. loff in ushorts within a 36864-ushort buffer.
  const unsigned short* gch[9];
  int loff[9];
#pragma unroll
  for (int j = 0; j < 9; ++j) {
    const int c = wave * 9 + j;
    const unsigned short* base; int row0, toff, rg;
    if (c < 16)      { base = Xhi;  row0 = m0; toff = 0;     rg = c; }
    else if (c < 32) { base = Xlo;  row0 = m0; toff = 8192;  rg = c - 16; }
    else if (c < 40) { base = Wq_h; row0 = n0; toff = 16384; rg = c - 32; }
    else if (c < 48) { base = Wq_l; row0 = n0; toff = 20480; rg = c - 40; }
    else if (c < 56) { base = Wk_h; row0 = n0; toff = 24576; rg = c - 48; }
    else if (c < 64) { base = Wk_l; row0 = n0; toff = 28672; rg = c - 56; }
    else             { base = Wv_h; row0 = n0; toff = 32768; rg = c - 64; }
    gch[j] = base + (size_t)(row0 + rg * 16 + (lane >> 2)) * K + DMA_COL(lane);
    loff[j] = toff + rg * 512;
  }
  f32x4 aq[4][4] = {}, ak[4][4] = {}, av[4][4] = {};

  {  // prologue: stage buffer 0 fully
#pragma unroll
    for (int j = 0; j < 9; ++j)
      ld_lds16(gch[j], sm + loff[j]);
    asm volatile("s_waitcnt vmcnt(0)" ::: "memory");
    __builtin_amdgcn_s_barrier();
    __builtin_amdgcn_sched_barrier(0);
  }
  int cur = 0;
  for (int tix = 0; tix < 64; ++tix) {
    const int nk = (tix + 1) * 32;
    const unsigned short* bufp = sm + cur * 36864;
    unsigned short* nbuf = sm + (cur ^ 1) * 36864;
    if (tix + 1 < 64) {  // first half of next-step stage
#pragma unroll
      for (int j = 0; j < 5; ++j)
        ld_lds16(gch[j] + nk, nbuf + loff[j]);
    }
    bf16x8 ah[4], al[4], bh[4], bl[4];
#pragma unroll
    for (int mb = 0; mb < 4; ++mb) {
      ah[mb] = *(const bf16x8*)&bufp[(wm + mb * 16 + l15) * 32 + cq0];
      al[mb] = *(const bf16x8*)&bufp[8192 + (wm + mb * 16 + l15) * 32 + cq0];
    }
#pragma unroll
    for (int nb = 0; nb < 4; ++nb) {
      bh[nb] = *(const bf16x8*)&bufp[16384 + (wn + nb * 16 + l15) * 32 + cq0];
      bl[nb] = *(const bf16x8*)&bufp[20480 + (wn + nb * 16 + l15) * 32 + cq0];
    }
    __builtin_amdgcn_s_setprio(1);
#pragma unroll
    for (int mb = 0; mb < 4; ++mb)
#pragma unroll
      for (int nb = 0; nb < 4; ++nb) {
        aq[mb][nb] = __builtin_amdgcn_mfma_f32_16x16x32_bf16(ah[mb], bh[nb], aq[mb][nb], 0, 0, 0);
        aq[mb][nb] = __builtin_amdgcn_mfma_f32_16x16x32_bf16(ah[mb], bl[nb], aq[mb][nb], 0, 0, 0);
        aq[mb][nb] = __builtin_amdgcn_mfma_f32_16x16x32_bf16(al[mb], bh[nb], aq[mb][nb], 0, 0, 0);
      }
    __builtin_amdgcn_s_setprio(0);
    if (tix + 1 < 64) {  // second half of next-step stage
#pragma unroll
      for (int j = 5; j < 9; ++j)
        ld_lds16(gch[j] + nk, nbuf + loff[j]);
    }
    __builtin_amdgcn_sched_barrier(0);   // cluster split: bound reg pressure
#pragma unroll
    for (int nb = 0; nb < 4; ++nb) {
      bh[nb] = *(const bf16x8*)&bufp[24576 + (wn + nb * 16 + l15) * 32 + cq0];
      bl[nb] = *(const bf16x8*)&bufp[28672 + (wn + nb * 16 + l15) * 32 + cq0];
    }
    __builtin_amdgcn_s_setprio(1);
#pragma unroll
    for (int mb = 0; mb < 4; ++mb)
#pragma unroll
      for (int nb = 0; nb < 4; ++nb) {
        ak[mb][nb] = __builtin_amdgcn_mfma_f32_16x16x32_bf16(ah[mb], bh[nb], ak[mb][nb], 0, 0, 0);
        ak[mb][nb] = __builtin_amdgcn_mfma_f32_16x16x32_bf16(ah[mb], bl[nb], ak[mb][nb], 0, 0, 0);
        ak[mb][nb] = __builtin_amdgcn_mfma_f32_16x16x32_bf16(al[mb], bh[nb], ak[mb][nb], 0, 0, 0);
      }
    __builtin_amdgcn_s_setprio(0);
    __builtin_amdgcn_sched_barrier(0);   // cluster split
#pragma unroll
    for (int nb = 0; nb < 4; ++nb)
      bh[nb] = *(const bf16x8*)&bufp[32768 + (wn + nb * 16 + l15) * 32 + cq0];
    __builtin_amdgcn_s_setprio(1);
#pragma unroll
    for (int mb = 0; mb < 4; ++mb)
#pragma unroll
      for (int nb = 0; nb < 4; ++nb)
        av[mb][nb] = __builtin_amdgcn_mfma_f32_16x16x32_bf16(ah[mb], bh[nb], av[mb][nb], 0, 0, 0);
    __builtin_amdgcn_s_setprio(0);
    if (tix + 1 < 64) {
      asm volatile("s_waitcnt vmcnt(0)" ::: "memory");
      __builtin_amdgcn_s_barrier();
      __builtin_amdgcn_sched_barrier(0);
    }
    cur ^= 1;
  }
  // epilogue 1: write Q (scaled) and K, each split hi/lo (global only)
#pragma unroll
  for (int mb = 0; mb < 4; ++mb)
#pragma unroll
    for (int nb = 0; nb < 4; ++nb)
#pragma unroll
      for (int r = 0; r < 4; ++r) {
        int row = m0 + wm + mb * 16 + quad * 4 + r;
        int col = n0 + wn + nb * 16 + l15;
        float vq = aq[mb][nb][r] * qscale;
        unsigned short hq = f2bf(vq);
        Qhi[(size_t)row * N + col] = hq;
        Qlo[(size_t)row * N + col] = f2bf(vq - bf2f(hq));
        float vk = ak[mb][nb][r];
        unsigned short hk = f2bf(vk);
        Khi[(size_t)row * N + col] = hk;
        Klo[(size_t)row * N + col] = f2bf(vk - bf2f(hk));
      }
  // epilogue 2: V^T via LDS (stride 264), coalesced stores
  __syncthreads();   // all LDS reads done before overwriting sm
#pragma unroll
  for (int mb = 0; mb < 4; ++mb)
#pragma unroll
    for (int nb = 0; nb < 4; ++nb) {
      ushort4 pk;
      pk.x = f2bf(av[mb][nb][0]);
      pk.y = f2bf(av[mb][nb][1]);
      pk.z = f2bf(av[mb][nb][2]);
      pk.w = f2bf(av[mb][nb][3]);
      *(ushort4*)&sm[(wn + nb * 16 + l15) * 264 + wm + mb * 16 + quad * 4] = pk;
    }
  __syncthreads();
  const int bb = m0 >> 11;          // batch index (BM=256 never straddles)
  const int mloc = m0 & 2047;
  unsigned short* Vb = Vt + (size_t)bb * 2048 * 2048;
#pragma unroll
  for (int jj = 0; jj < 8; ++jj) {
    int idx2 = jj * 512 + t;         // [0,4096): 128 rows x 32 units of 16B
    int n = idx2 >> 5, mu = idx2 & 31;
    uint4 v = *(uint4*)&sm[n * 264 + mu * 8];
    *(uint4*)(Vb + (size_t)(n0 + n) * 2048 + mloc + mu * 8) = v;
  }
}

// out-projection: C(MxN) = A @ B^T, fp32 partials, K-slice by z.
__global__ __launch_bounds__(256) void gemm_out(
    const unsigned short* __restrict__ Ahi, const unsigned short* __restrict__ Bhi,
    float* __restrict__ out, int M, int N, int K, int ldk) {
  __shared__ unsigned short sm[8192];
  unsigned short* Ah = sm;
  unsigned short* Bh = sm + 4096;
  const int z = blockIdx.z;
  const int t = threadIdx.x;
  const int wave = t >> 6, lane = t & 63, quad = lane >> 4, l15 = lane & 15;
  const int wm = (wave & 1) * 64, wn = (wave >> 1) * 64;
  const int m0 = blockIdx.y * 128, n0 = blockIdx.x * 128;
  const int cq0 = (quad * 8) ^ SWZ(l15);
  const unsigned short* gsrc = (wave < 2) ? Ahi : Bhi;
  unsigned short* ldst = (wave < 2) ? Ah : Bh;
  const int row0 = (wave < 2) ? m0 : n0;
  const int jb = (wave & 1) * 4;
  const unsigned short* gbase = gsrc + (size_t)(row0 + (lane >> 2)) * K + DMA_COL(lane);
  f32x4 acc[4][4] = {};
  for (int k0 = z * ldk; k0 < (z + 1) * ldk; k0 += 32) {
#pragma unroll
    for (int j = 0; j < 4; ++j)
      ld_lds16(gbase + (size_t)((jb + j) * 16) * K + k0, ldst + (jb + j) * 512);
    __syncthreads();
    bf16x8 ah[4], bh[4];
#pragma unroll
    for (int mb = 0; mb < 4; ++mb)
      ah[mb] = *(bf16x8*)&Ah[(wm + mb * 16 + l15) * 32 + cq0];
#pragma unroll
    for (int nb = 0; nb < 4; ++nb)
      bh[nb] = *(bf16x8*)&Bh[(wn + nb * 16 + l15) * 32 + cq0];
#pragma unroll
    for (int mb = 0; mb < 4; ++mb)
#pragma unroll
      for (int nb = 0; nb < 4; ++nb)
        acc[mb][nb] = __builtin_amdgcn_mfma_f32_16x16x32_bf16(ah[mb], bh[nb], acc[mb][nb], 0, 0, 0);
    __syncthreads();
  }
  float* of = out + (size_t)z * M * N;
#pragma unroll
  for (int mb = 0; mb < 4; ++mb)
#pragma unroll
    for (int nb = 0; nb < 4; ++nb)
#pragma unroll
      for (int r = 0; r < 4; ++r) {
        int row = m0 + wm + mb * 16 + quad * 4 + r;
        int col = n0 + wn + nb * 16 + l15;
        of[(size_t)row * N + col] = acc[mb][nb][r];
      }
}

// sum nsl fp32 partial slices -> out
__global__ __launch_bounds__(256) void reduceN(const float* __restrict__ p,
                                               float* __restrict__ out, int n, int nsl) {
  int i = (blockIdx.x * 256 + threadIdx.x) * 4;
  if (i >= n) return;
  float4 acc = *(const float4*)(p + i);
  for (int s = 1; s < nsl; ++s) {
    float4 v = *(const float4*)(p + (size_t)s * n + i);
    acc.x += v.x; acc.y += v.y; acc.z += v.z; acc.w += v.w;
  }
  *(float4*)(out + i) = acc;
}

// Flash attention, transposed-score (S^T = K*Q^T), QBLK=128.
// Block: 1 head, 128 q as TWO 64-q groups; 4 waves x (16 q per group).
// K/V fragments are read from LDS ONCE per tile and reused for both groups.
// 32-key tiles, 3-buffer depth-2 DMA pipeline with counted vmcnt(6) + raw
// s_barrier; setprio around MFMA; defer-max (T13).
// Batched: blockIdx.x>>8 selects batch (256 blocks/batch).
__global__ __launch_bounds__(256, 2) void attn_mfma(
    const unsigned short* __restrict__ Qhi, const unsigned short* __restrict__ Qlo,
    const unsigned short* __restrict__ Khi, const unsigned short* __restrict__ Klo,
    const unsigned short* __restrict__ Vt, unsigned short* __restrict__ Ob, int S) {
  __shared__ unsigned short Kh_s[3 * 4096];  // per buf: 4 chunks [32 keys x 32 dims]
  __shared__ unsigned short Kl_s[3 * 4096];
  __shared__ unsigned short V_s[3 * 4096];   // per buf: [128 dims x 32 keys]
  __shared__ unsigned short P_s[4 * 640];    // per wave: [16 q x 40 keys(pad)]
  const int t = threadIdx.x;
  const int wave = t >> 6, lane = t & 63, quad = lane >> 4, l15 = lane & 15;
  const int bidall = blockIdx.x;
  const size_t boff = (size_t)(bidall >> 8) * (2048 * 2048);
  Qhi += boff; Qlo += boff; Khi += boff; Klo += boff; Vt += boff; Ob += boff;
  const int bid = bidall & 255;
  const int xcd = bid & 7, slot = bid >> 3;   // slot in [0,32)
  const int head = (xcd << 1) | (slot >> 4);  // 2 heads per XCD -> K/V in L2
  const int qblk = slot & 15;                 // 16 q-blocks of 128
  const size_t hoff = (size_t)head * 128;
  const int cq0 = (quad * 8) ^ SWZ(l15);

  bf16x8 qh[2][4], ql[2][4];
#pragma unroll
  for (int g = 0; g < 2; ++g) {
    const int qb = qblk * 128 + g * 64 + wave * 16;
#pragma unroll
    for (int kb = 0; kb < 4; ++kb) {
      size_t off = (size_t)(qb + l15) * 2048 + hoff + kb * 32 + quad * 8;
      qh[g][kb] = *(const bf16x8*)(Qhi + off);
      ql[g][kb] = *(const bf16x8*)(Qlo + off);
    }
  }
  f32x4 o[2][8] = {};   // per group: O^T[d = rb*16+quad*4+r][q = l15]
  float m_run[2] = {-INFINITY, -INFINITY}, l_run[2] = {0.f, 0.f};

  const int lr = lane >> 2, lc = DMA_COL(lane);
  const unsigned short* gKh = Khi + (size_t)lr * 2048 + hoff + wave * 32 + lc;
  const unsigned short* gKl = Klo + (size_t)lr * 2048 + hoff + wave * 32 + lc;
  const unsigned short* gV  = Vt + (hoff + wave * 32 + lr) * (size_t)S + lc;
  unsigned short* Pw = P_s + wave * 640;

  auto stage = [&](int buf, int kpos) {
    const int b4 = buf * 4096 + wave * 1024;
#pragma unroll
    for (int i = 0; i < 2; ++i) {
      ld_lds16(gKh + (size_t)(kpos + i * 16) * 2048, Kh_s + b4 + i * 512);
      ld_lds16(gKl + (size_t)(kpos + i * 16) * 2048, Kl_s + b4 + i * 512);
      ld_lds16(gV + (size_t)(i * 16) * S + kpos,      V_s + b4 + i * 512);
    }
  };
  stage(0, 0);
  stage(1, 32);
  asm volatile("s_waitcnt vmcnt(6)" ::: "memory");
  __builtin_amdgcn_s_barrier();
  __builtin_amdgcn_sched_barrier(0);

  int cur = 0, st = 2;
  for (int tix = 0; tix < 64; ++tix) {
    if (tix + 2 < 64) stage(st, (tix + 2) * 32);
    const int cb = cur * 4096;
    f32x4 s[2][2] = {};
    __builtin_amdgcn_s_setprio(1);
#pragma unroll
    for (int mb = 0; mb < 2; ++mb)
#pragma unroll
      for (int kb = 0; kb < 4; ++kb) {
        bf16x8 kh = *(bf16x8*)&Kh_s[cb + kb * 1024 + (mb * 16 + l15) * 32 + cq0];
        bf16x8 kl = *(bf16x8*)&Kl_s[cb + kb * 1024 + (mb * 16 + l15) * 32 + cq0];
        s[0][mb] = __builtin_amdgcn_mfma_f32_16x16x32_bf16(kh, qh[0][kb], s[0][mb], 0, 0, 0);
        s[0][mb] = __builtin_amdgcn_mfma_f32_16x16x32_bf16(kh, ql[0][kb], s[0][mb], 0, 0, 0);
        s[0][mb] = __builtin_amdgcn_mfma_f32_16x16x32_bf16(kl, qh[0][kb], s[0][mb], 0, 0, 0);
        s[1][mb] = __builtin_amdgcn_mfma_f32_16x16x32_bf16(kh, qh[1][kb], s[1][mb], 0, 0, 0);
        s[1][mb] = __builtin_amdgcn_mfma_f32_16x16x32_bf16(kh, ql[1][kb], s[1][mb], 0, 0, 0);
        s[1][mb] = __builtin_amdgcn_mfma_f32_16x16x32_bf16(kl, qh[1][kb], s[1][mb], 0, 0, 0);
      }
    __builtin_amdgcn_s_setprio(0);

    bf16x8 pf[2];
#pragma unroll
    for (int g = 0; g < 2; ++g) {
      float mt = s[g][0][0];
#pragma unroll
      for (int r = 1; r < 4; ++r) mt = fmaxf(mt, s[g][0][r]);
#pragma unroll
      for (int r = 0; r < 4; ++r) mt = fmaxf(mt, s[g][1][r]);
      mt = fmaxf(mt, __shfl_xor(mt, 16));
      mt = fmaxf(mt, __shfl_xor(mt, 32));
      // defer-max: rescale only when some query's max grew by > 8 (base-2)
      if (!__all(mt <= m_run[g] + 8.f)) {
        const float m_new = fmaxf(m_run[g], mt);
        const float alpha = __builtin_amdgcn_exp2f(m_run[g] - m_new);
        l_run[g] *= alpha;
#pragma unroll
        for (int rb = 0; rb < 8; ++rb)
#pragma unroll
          for (int r = 0; r < 4; ++r) o[g][rb][r] *= alpha;
        m_run[g] = m_new;
      }
      float p[8];
#pragma unroll
      for (int mb = 0; mb < 2; ++mb)
#pragma unroll
        for (int r = 0; r < 4; ++r)
          p[mb * 4 + r] = __builtin_amdgcn_exp2f(s[g][mb][r] - m_run[g]);
      float rs = p[0];
#pragma unroll
      for (int j = 1; j < 8; ++j) rs += p[j];
      rs += __shfl_xor(rs, 16);
      rs += __shfl_xor(rs, 32);
      l_run[g] += rs;
#pragma unroll
      for (int mb = 0; mb < 2; ++mb) {
        ushort4 pk;
        pk.x = f2bf(p[mb * 4 + 0]);
        pk.y = f2bf(p[mb * 4 + 1]);
        pk.z = f2bf(p[mb * 4 + 2]);
        pk.w = f2bf(p[mb * 4 + 3]);
        *(ushort4*)&Pw[l15 * 40 + mb * 16 + quad * 4] = pk;
      }
      pf[g] = *(bf16x8*)&Pw[l15 * 40 + quad * 8];  // same-wave DS in-order
    }
    __builtin_amdgcn_s_setprio(1);
#pragma unroll
    for (int rb = 0; rb < 8; ++rb) {
      bf16x8 vb = *(bf16x8*)&V_s[cb + (rb * 16 + l15) * 32 + cq0];
      o[0][rb] = __builtin_amdgcn_mfma_f32_16x16x32_bf16(vb, pf[0], o[0][rb], 0, 0, 0);
      o[1][rb] = __builtin_amdgcn_mfma_f32_16x16x32_bf16(vb, pf[1], o[1][rb], 0, 0, 0);
    }
    __builtin_amdgcn_s_setprio(0);
    if (tix + 2 < 64) asm volatile("s_waitcnt vmcnt(6)" ::: "memory");
    else              asm volatile("s_waitcnt vmcnt(0)" ::: "memory");
    __builtin_amdgcn_s_barrier();
    __builtin_amdgcn_sched_barrier(0);
    cur = cur == 2 ? 0 : cur + 1;
    st = st == 2 ? 0 : st + 1;
  }
#pragma unroll
  for (int g = 0; g < 2; ++g) {
    const int qb = qblk * 128 + g * 64 + wave * 16;
    const float inv = 1.0f / l_run[g];
#pragma unroll
    for (int rb = 0; rb < 8; ++rb) {
      ushort4 pk;
      pk.x = f2bf(o[g][rb][0] * inv);
      pk.y = f2bf(o[g][rb][1] * inv);
      pk.z = f2bf(o[g][rb][2] * inv);
      pk.w = f2bf(o[g][rb][3] * inv);
      *(ushort4*)(Ob + (size_t)(qb + l15) * 2048 + hoff + rb * 16 + quad * 4) = pk;
    }
  }
}

extern "C" void kernel_launch(void* const* d_in, const int* in_sizes, int n_in,
                              void* d_out, int out_size, void* d_ws, size_t ws_size,
                              hipStream_t stream) {
  (void)in_sizes; (void)n_in; (void)out_size;
  const float* X   = (const float*)d_in[0];
  const float* W_Q = (const float*)d_in[2];
  const float* W_K = (const float*)d_in[3];
  const float* W_V = (const float*)d_in[4];
  const float* W_O = (const float*)d_in[5];
  float* out = (float*)d_out;

  const int S = 2048, HD = 2048;
  const size_t P = (size_t)HD * HD;
  unsigned short* w = (unsigned short*)d_ws;
  unsigned short* WqThi = w;
  unsigned short* WqTlo = w + P;
  unsigned short* WkThi = w + 2 * P;
  unsigned short* WkTlo = w + 3 * P;
  unsigned short* WvThi = w + 4 * P;
  unsigned short* WoThi = w + 5 * P;   // 128 x 2048 (N x K)
  unsigned short* base6 = w + 5 * P + P / 16;

  // log2(e)/sqrt(128) folded into Q at projection time (base-2 softmax)
  const float qscale = 0.12752551286084109f;

  dim3 bT(32, 8);
  tsplit<true ><<<dim3(64, 64), bT, 0, stream>>>(W_Q, WqThi, WqTlo, HD, HD);
  tsplit<true ><<<dim3(64, 64), bT, 0, stream>>>(W_K, WkThi, WkTlo, HD, HD);
  tsplit<false><<<dim3(64, 64), bT, 0, stream>>>(W_V, WvThi, nullptr, HD, HD);
  tsplit<false><<<dim3(4, 64),  bT, 0, stream>>>(W_O, WoThi, nullptr, HD, 128);

  // tiers: chunk of C batches needs (5P + P/16 + 7*C*P) elements * 2 bytes
  const size_t elW = 5 * P + P / 16;
  const size_t need2 = (elW + 14 * P) * 2;   // ~160 MB
  const size_t need1 = (elW + 7 * P) * 2;    // ~101 MB
  int C; bool tight = false;
  if (ws_size >= need2)      C = 2;
  else if (ws_size >= need1) C = 1;
  else { C = 1; tight = true; }              // tight layout (Vt=Xlo)

  const size_t CP = (size_t)C * P;
  unsigned short* Xhi = base6;
  unsigned short* Xlo = base6 + CP;
  unsigned short* Qhi = base6 + 2 * CP;
  unsigned short* Qlo = base6 + 3 * CP;
  unsigned short* Khi = base6 + 4 * CP;
  unsigned short* Klo = base6 + 5 * CP;
  unsigned short* Vt  = tight ? Xlo : base6 + 6 * CP;
  unsigned short* attnB = Xhi;            // alias: X dead after QKV
  float* fpart = (float*)Qhi;             // alias: Q/K dead after attn (4CP span)

  const int M = C * S;                    // chunk rows
  const int zn = 16 / C;                  // gemm_out K-slices -> 256 blocks
  const int ldk = HD / zn;
  const int NOUT = M * 128;

  for (int c = 0; c < 4 / C; ++c) {
    split_f32<<<C * 4096, 256, 0, stream>>>(X + (size_t)c * CP, Xhi, Xlo, (int)CP);
    gemm_qkv4<<<dim3(16, C * 8), 512, 0, stream>>>(
        Xhi, Xlo, WqThi, WqTlo, WkThi, WkTlo, WvThi,
        Qhi, Qlo, Khi, Klo, Vt, qscale);
    attn_mfma<<<C * 256, 256, 0, stream>>>(Qhi, Qlo, Khi, Klo, Vt, attnB, S);
    gemm_out<<<dim3(1, C * 16, zn), 256, 0, stream>>>(attnB, WoThi, fpart, M, 128, HD, ldk);
    reduceN<<<NOUT / 1024, 256, 0, stream>>>(fpart, out + (size_t)c * NOUT, NOUT, zn);
  }
}

// Round 9
// 870.175 us; speedup vs baseline: 1.4827x; 1.4827x over previous
//
#include <hip/hip_runtime.h>
#include <cstdint>
#include <math.h>

typedef short bf16x8 __attribute__((ext_vector_type(8)));
typedef float f32x4 __attribute__((ext_vector_type(4)));

__device__ __forceinline__ unsigned short f2bf(float x) {
  union { float f; uint32_t u; } v; v.f = x;
  return (unsigned short)((v.u + 0x7FFFu + ((v.u >> 16) & 1u)) >> 16);
}
__device__ __forceinline__ float bf2f(unsigned short h) {
  union { uint32_t u; float f; } v; v.u = ((uint32_t)h) << 16;
  return v.f;
}

// async global->LDS, 16B per lane (global_load_lds_dwordx4). LDS dest is
// wave-uniform base; HW writes base + lane*16.
__device__ __forceinline__ void ld_lds16(const unsigned short* g, unsigned short* l) {
  auto gp = (const __attribute__((address_space(1))) unsigned short*)(uintptr_t)g;
  auto lp = (__attribute__((address_space(3))) unsigned short*)(uint32_t)(uintptr_t)l;
  __builtin_amdgcn_global_load_lds(gp, lp, 16, 0, 0);
}

// 32-col tiles (64B rows = 4 chunks of 16B): XOR-swizzle chunk with (row>>1)&3.
// DMA writes LDS linearly, so the swizzle is applied to the per-lane GLOBAL
// source column; read applies the same XOR -> 2-way max bank conflicts.
#define DMA_COL(lane) ((((lane) & 3) ^ (((lane) >> 3) & 3)) * 8)
#define SWZ(l15) ((((l15) >> 1) & 3) * 8)
// 64-col tiles (128B rows = 8 chunks of 16B): XOR chunk with row&7.
#define DMA_COL64(lane) ((((lane) & 7) ^ (((lane) >> 3) & 7)) * 8)

// split fp32 -> bf16 hi + bf16 lo (residual)
__global__ __launch_bounds__(256) void split_f32(const float* __restrict__ src,
                                                 unsigned short* __restrict__ hi,
                                                 unsigned short* __restrict__ lo, int n) {
  int i = (blockIdx.x * 256 + threadIdx.x) * 4;
  if (i >= n) return;
  float4 v = *(const float4*)(src + i);
  ushort4 h, l;
  h.x = f2bf(v.x); l.x = f2bf(v.x - bf2f(h.x));
  h.y = f2bf(v.y); l.y = f2bf(v.y - bf2f(h.y));
  h.z = f2bf(v.z); l.z = f2bf(v.z - bf2f(h.z));
  h.w = f2bf(v.w); l.w = f2bf(v.w - bf2f(h.w));
  *(ushort4*)(hi + i) = h;
  *(ushort4*)(lo + i) = l;
}

// transpose W (K x N) -> hiT/loT (N x K) bf16
template<bool LO>
__global__ __launch_bounds__(256) void tsplit(const float* __restrict__ W,
                                              unsigned short* __restrict__ hiT,
                                              unsigned short* __restrict__ loT,
                                              int K, int N) {
  __shared__ float tile[32][33];
  const int tx = threadIdx.x, ty = threadIdx.y;  // 32 x 8
  const int bx = blockIdx.x, by = blockIdx.y;
#pragma unroll
  for (int i = 0; i < 4; ++i)
    tile[ty + i * 8][tx] = W[(size_t)(by * 32 + ty + i * 8) * N + bx * 32 + tx];
  __syncthreads();
#pragma unroll
  for (int i = 0; i < 4; ++i) {
    float v = tile[tx][ty + i * 8];
    size_t o = (size_t)(bx * 32 + ty + i * 8) * K + by * 32 + tx;
    unsigned short h = f2bf(v);
    hiT[o] = h;
    if (LO) loT[o] = f2bf(v - bf2f(h));
  }
}

// Fused Q/K/V projection v3: MERGED Q+K blocks.
// z=0: one block computes BOTH Q and K 256x128 tiles, staging X (hi/lo) ONCE
//      plus 4 weight tiles = 64KB/step feeding 768 MFMAs. 2 LDS buffers x
//      64KB, depth-1 prefetch, vmcnt(0)+barrier per step. Two MFMA clusters
//      (Q, K) split by sched_barrier. NOTE (round-8 lesson): do NOT merge V
//      here too — a third accumulator set (192 acc + 64 operand regs) blows
//      the 256/wave unified VGPR budget at 512-thread blocks and spills acc
//      to scratch (+760MB HBM traffic, MfmaUtil 53->23%).
// z=1: V single product, BK=64, 2 buffers x 48KB depth-1, V^T out per batch.
// Balanced per-z XCD swizzle: each XCD gets equal slices of both z-planes.
__global__ __launch_bounds__(512, 2) void gemm_qkv3(
    const unsigned short* __restrict__ Xhi, const unsigned short* __restrict__ Xlo,
    const unsigned short* __restrict__ Wq_h, const unsigned short* __restrict__ Wq_l,
    const unsigned short* __restrict__ Wk_h, const unsigned short* __restrict__ Wk_l,
    const unsigned short* __restrict__ Wv_h,
    unsigned short* __restrict__ Qhi, unsigned short* __restrict__ Qlo,
    unsigned short* __restrict__ Khi, unsigned short* __restrict__ Klo,
    unsigned short* __restrict__ Vt, float qscale) {
  __shared__ unsigned short sm[65536];  // 128 KiB
  const int K = 2048, N = 2048;
  // balanced per-z XCD swizzle (bijective; gx*gy divisible by 8)
  const int gx = gridDim.x, gy = gridDim.y;
  const int perz = (gx * gy) >> 3;          // units per XCD per z-plane
  const int lid = blockIdx.x + gx * (blockIdx.y + gy * blockIdx.z);
  const int xcd = lid & 7, idx = lid >> 3;
  const int z = idx / perz;
  const int wiz = xcd * perz + (idx - z * perz);
  const int bx = wiz % gx;
  const int by = wiz / gx;
  const int t = threadIdx.x;
  const int wave = t >> 6, lane = t & 63, quad = lane >> 4, l15 = lane & 15;
  const int m0 = by * 256, n0 = bx * 128;
  const int wm = (wave >> 1) * 64, wn = (wave & 1) * 64;

  if (z == 0) {  // ---- merged Q+K: 3-product split, BK=32 ----
    const int cq0 = (quad * 8) ^ SWZ(l15);
    // 64 wave-load chunks/step (Ah 16, Al 16, Bqh 8, Bql 8, Bkh 8, Bkl 8)
    const unsigned short* gch[8];
    int loff[8];
#pragma unroll
    for (int j = 0; j < 8; ++j) {
      const int c = wave * 8 + j;
      const unsigned short* base; int row0, toff, rg;
      if (c < 16)      { base = Xhi;  row0 = m0; toff = 0;     rg = c; }
      else if (c < 32) { base = Xlo;  row0 = m0; toff = 8192;  rg = c - 16; }
      else if (c < 40) { base = Wq_h; row0 = n0; toff = 16384; rg = c - 32; }
      else if (c < 48) { base = Wq_l; row0 = n0; toff = 20480; rg = c - 40; }
      else if (c < 56) { base = Wk_h; row0 = n0; toff = 24576; rg = c - 48; }
      else             { base = Wk_l; row0 = n0; toff = 28672; rg = c - 56; }
      gch[j] = base + (size_t)(row0 + rg * 16 + (lane >> 2)) * K + DMA_COL(lane);
      loff[j] = toff + rg * 512;
    }
    auto stage = [&](int buf, int k0) {
#pragma unroll
      for (int j = 0; j < 8; ++j)
        ld_lds16(gch[j] + k0, sm + buf * 32768 + loff[j]);
    };
    f32x4 aq[4][4] = {}, ak[4][4] = {};
    stage(0, 0);
    asm volatile("s_waitcnt vmcnt(0)" ::: "memory");
    __builtin_amdgcn_s_barrier();
    __builtin_amdgcn_sched_barrier(0);
    int cur = 0;
    for (int tix = 0; tix < 64; ++tix) {
      if (tix + 1 < 64) stage(cur ^ 1, (tix + 1) * 32);
      const unsigned short* bufp = sm + cur * 32768;
      bf16x8 ah[4], al[4], bh[4], bl[4];
#pragma unroll
      for (int mb = 0; mb < 4; ++mb) {
        ah[mb] = *(const bf16x8*)&bufp[(wm + mb * 16 + l15) * 32 + cq0];
        al[mb] = *(const bf16x8*)&bufp[8192 + (wm + mb * 16 + l15) * 32 + cq0];
      }
#pragma unroll
      for (int nb = 0; nb < 4; ++nb) {
        bh[nb] = *(const bf16x8*)&bufp[16384 + (wn + nb * 16 + l15) * 32 + cq0];
        bl[nb] = *(const bf16x8*)&bufp[20480 + (wn + nb * 16 + l15) * 32 + cq0];
      }
      __builtin_amdgcn_s_setprio(1);
#pragma unroll
      for (int mb = 0; mb < 4; ++mb)
#pragma unroll
        for (int nb = 0; nb < 4; ++nb) {
          aq[mb][nb] = __builtin_amdgcn_mfma_f32_16x16x32_bf16(ah[mb], bh[nb], aq[mb][nb], 0, 0, 0);
          aq[mb][nb] = __builtin_amdgcn_mfma_f32_16x16x32_bf16(ah[mb], bl[nb], aq[mb][nb], 0, 0, 0);
          aq[mb][nb] = __builtin_amdgcn_mfma_f32_16x16x32_bf16(al[mb], bh[nb], aq[mb][nb], 0, 0, 0);
        }
      __builtin_amdgcn_s_setprio(0);
      __builtin_amdgcn_sched_barrier(0);   // phase split: bounds reg pressure
#pragma unroll
      for (int nb = 0; nb < 4; ++nb) {
        bh[nb] = *(const bf16x8*)&bufp[24576 + (wn + nb * 16 + l15) * 32 + cq0];
        bl[nb] = *(const bf16x8*)&bufp[28672 + (wn + nb * 16 + l15) * 32 + cq0];
      }
      __builtin_amdgcn_s_setprio(1);
#pragma unroll
      for (int mb = 0; mb < 4; ++mb)
#pragma unroll
        for (int nb = 0; nb < 4; ++nb) {
          ak[mb][nb] = __builtin_amdgcn_mfma_f32_16x16x32_bf16(ah[mb], bh[nb], ak[mb][nb], 0, 0, 0);
          ak[mb][nb] = __builtin_amdgcn_mfma_f32_16x16x32_bf16(ah[mb], bl[nb], ak[mb][nb], 0, 0, 0);
          ak[mb][nb] = __builtin_amdgcn_mfma_f32_16x16x32_bf16(al[mb], bh[nb], ak[mb][nb], 0, 0, 0);
        }
      __builtin_amdgcn_s_setprio(0);
      if (tix + 1 < 64) {
        asm volatile("s_waitcnt vmcnt(0)" ::: "memory");
        __builtin_amdgcn_s_barrier();
        __builtin_amdgcn_sched_barrier(0);
      }
      cur ^= 1;
    }
    // epilogue: write Q (scaled) and K, each split hi/lo
#pragma unroll
    for (int mb = 0; mb < 4; ++mb)
#pragma unroll
      for (int nb = 0; nb < 4; ++nb)
#pragma unroll
        for (int r = 0; r < 4; ++r) {
          int row = m0 + wm + mb * 16 + quad * 4 + r;
          int col = n0 + wn + nb * 16 + l15;
          float vq = aq[mb][nb][r] * qscale;
          unsigned short hq = f2bf(vq);
          Qhi[(size_t)row * N + col] = hq;
          Qlo[(size_t)row * N + col] = f2bf(vq - bf2f(hq));
          float vk = ak[mb][nb][r];
          unsigned short hk = f2bf(vk);
          Khi[(size_t)row * N + col] = hk;
          Klo[(size_t)row * N + col] = f2bf(vk - bf2f(hk));
        }
  } else {  // ---- V: single product, BK=64, V^T out per batch ----
    const unsigned short* gch[6];
    int loff[6];
#pragma unroll
    for (int j = 0; j < 6; ++j) {
      const int c = wave * 6 + j;
      const unsigned short* base; int row0, toff, rg;
      if (c < 32) { base = Xhi;  row0 = m0; toff = 0;     rg = c; }
      else        { base = Wv_h; row0 = n0; toff = 16384; rg = c - 32; }
      gch[j] = base + (size_t)(row0 + rg * 8 + (lane >> 3)) * K + DMA_COL64(lane);
      loff[j] = toff + rg * 512;
    }
    auto stage = [&](int buf, int k0) {
#pragma unroll
      for (int j = 0; j < 6; ++j)
        ld_lds16(gch[j] + k0, sm + buf * 24576 + loff[j]);
    };
    f32x4 acc[4][4] = {};
    stage(0, 0);
    asm volatile("s_waitcnt vmcnt(0)" ::: "memory");
    __builtin_amdgcn_s_barrier();
    __builtin_amdgcn_sched_barrier(0);
    int cur = 0;
    for (int tix = 0; tix < 32; ++tix) {
      if (tix + 1 < 32) stage(cur ^ 1, (tix + 1) * 64);
      const unsigned short* bufp = sm + cur * 24576;
      bf16x8 a[2][4], b[2][4];
#pragma unroll
      for (int kk = 0; kk < 2; ++kk) {
#pragma unroll
        for (int mb = 0; mb < 4; ++mb) {
          const int row = wm + mb * 16 + l15;
          a[kk][mb] = *(const bf16x8*)&bufp[row * 64 + (((kk * 4 + quad) ^ (row & 7)) * 8)];
        }
#pragma unroll
        for (int nb = 0; nb < 4; ++nb) {
          const int row = wn + nb * 16 + l15;
          b[kk][nb] = *(const bf16x8*)&bufp[16384 + row * 64 + (((kk * 4 + quad) ^ (row & 7)) * 8)];
        }
      }
      __builtin_amdgcn_s_setprio(1);
#pragma unroll
      for (int kk = 0; kk < 2; ++kk)
#pragma unroll
        for (int mb = 0; mb < 4; ++mb)
#pragma unroll
          for (int nb = 0; nb < 4; ++nb)
            acc[mb][nb] = __builtin_amdgcn_mfma_f32_16x16x32_bf16(a[kk][mb], b[kk][nb], acc[mb][nb], 0, 0, 0);
      __builtin_amdgcn_s_setprio(0);
      if (tix + 1 < 32) {
        asm volatile("s_waitcnt vmcnt(0)" ::: "memory");
        __builtin_amdgcn_s_barrier();
        __builtin_amdgcn_sched_barrier(0);
      }
      cur ^= 1;
    }
    __syncthreads();   // all LDS reads done before epilogue overwrites sm
    // stage C^T tile (128 n x 256 m) into LDS (stride 264), coalesced V^T out
#pragma unroll
    for (int mb = 0; mb < 4; ++mb)
#pragma unroll
      for (int nb = 0; nb < 4; ++nb) {
        ushort4 pk;
        pk.x = f2bf(acc[mb][nb][0]);
        pk.y = f2bf(acc[mb][nb][1]);
        pk.z = f2bf(acc[mb][nb][2]);
        pk.w = f2bf(acc[mb][nb][3]);
        *(ushort4*)&sm[(wn + nb * 16 + l15) * 264 + wm + mb * 16 + quad * 4] = pk;
      }
    __syncthreads();
    const int bb = m0 >> 11;          // batch index (BM=256 never straddles)
    const int mloc = m0 & 2047;
    unsigned short* Vb = Vt + (size_t)bb * 2048 * 2048;
#pragma unroll
    for (int jj = 0; jj < 8; ++jj) {
      int idx2 = jj * 512 + t;         // [0,4096): 128 rows x 32 units of 16B
      int n = idx2 >> 5, mu = idx2 & 31;
      uint4 v = *(uint4*)&sm[n * 264 + mu * 8];
      *(uint4*)(Vb + (size_t)(n0 + n) * 2048 + mloc + mu * 8) = v;
    }
  }
}

// out-projection: C(MxN) = A @ B^T, fp32 partials, K-slice by z.
// 3-buffer depth-2 pipeline, counted vmcnt(4) + raw s_barrier (clone of the
// proven gemm_qkv2 loop; 4 staging loads/thread/step).
__global__ __launch_bounds__(256) void gemm_out(
    const unsigned short* __restrict__ Ahi, const unsigned short* __restrict__ Bhi,
    float* __restrict__ out, int M, int N, int K, int ldk) {
  __shared__ unsigned short sm[3 * 8192];
  const int z = blockIdx.z;
  const int t = threadIdx.x;
  const int wave = t >> 6, lane = t & 63, quad = lane >> 4, l15 = lane & 15;
  const int wm = (wave & 1) * 64, wn = (wave >> 1) * 64;
  const int m0 = blockIdx.y * 128, n0 = blockIdx.x * 128;
  const int cq0 = (quad * 8) ^ SWZ(l15);
  const unsigned short* gsrc = (wave < 2) ? Ahi : Bhi;
  const int boff = (wave < 2) ? 0 : 4096;
  const int row0 = (wave < 2) ? m0 : n0;
  const int jb = (wave & 1) * 4;
  const unsigned short* gbase = gsrc + (size_t)(row0 + (lane >> 2)) * K
                                + (size_t)z * ldk + DMA_COL(lane);
  const int nst = ldk / 32;
  auto stage = [&](int buf, int ks) {
#pragma unroll
    for (int j = 0; j < 4; ++j)
      ld_lds16(gbase + (size_t)((jb + j) * 16) * K + ks * 32,
               sm + buf * 8192 + boff + (jb + j) * 512);
  };
  f32x4 acc[4][4] = {};
  stage(0, 0);
  stage(1, 1);
  asm volatile("s_waitcnt vmcnt(4)" ::: "memory");
  __builtin_amdgcn_s_barrier();
  __builtin_amdgcn_sched_barrier(0);
  int cur = 0, st = 2;
  for (int tix = 0; tix < nst; ++tix) {
    if (tix + 2 < nst) stage(st, tix + 2);
    const unsigned short* bufp = sm + cur * 8192;
    bf16x8 ah[4], bh[4];
#pragma unroll
    for (int mb = 0; mb < 4; ++mb)
      ah[mb] = *(const bf16x8*)&bufp[(wm + mb * 16 + l15) * 32 + cq0];
#pragma unroll
    for (int nb = 0; nb < 4; ++nb)
      bh[nb] = *(const bf16x8*)&bufp[4096 + (wn + nb * 16 + l15) * 32 + cq0];
    __builtin_amdgcn_s_setprio(1);
#pragma unroll
    for (int mb = 0; mb < 4; ++mb)
#pragma unroll
      for (int nb = 0; nb < 4; ++nb)
        acc[mb][nb] = __builtin_amdgcn_mfma_f32_16x16x32_bf16(ah[mb], bh[nb], acc[mb][nb], 0, 0, 0);
    __builtin_amdgcn_s_setprio(0);
    if (tix + 2 < nst) asm volatile("s_waitcnt vmcnt(4)" ::: "memory");
    else               asm volatile("s_waitcnt vmcnt(0)" ::: "memory");
    __builtin_amdgcn_s_barrier();
    __builtin_amdgcn_sched_barrier(0);
    cur = cur == 2 ? 0 : cur + 1;
    st = st == 2 ? 0 : st + 1;
  }
  float* of = out + (size_t)z * M * N;
#pragma unroll
  for (int mb = 0; mb < 4; ++mb)
#pragma unroll
    for (int nb = 0; nb < 4; ++nb)
#pragma unroll
      for (int r = 0; r < 4; ++r) {
        int row = m0 + wm + mb * 16 + quad * 4 + r;
        int col = n0 + wn + nb * 16 + l15;
        of[(size_t)row * N + col] = acc[mb][nb][r];
      }
}

// sum nsl fp32 partial slices -> out
__global__ __launch_bounds__(256) void reduceN(const float* __restrict__ p,
                                               float* __restrict__ out, int n, int nsl) {
  int i = (blockIdx.x * 256 + threadIdx.x) * 4;
  if (i >= n) return;
  float4 acc = *(const float4*)(p + i);
  for (int s = 1; s < nsl; ++s) {
    float4 v = *(const float4*)(p + (size_t)s * n + i);
    acc.x += v.x; acc.y += v.y; acc.z += v.z; acc.w += v.w;
  }
  *(float4*)(out + i) = acc;
}

// Flash attention, transposed-score (S^T = K*Q^T), QBLK=128.
// Block: 1 head, 128 q as TWO 64-q groups; 4 waves x (16 q per group).
// K/V fragments are read from LDS ONCE per tile and reused for both groups.
// 32-key tiles, 3-buffer depth-2 DMA pipeline with counted vmcnt(6) + raw
// s_barrier; setprio around MFMA; defer-max (T13).
// Batched: blockIdx.x>>8 selects batch (256 blocks/batch).
__global__ __launch_bounds__(256, 2) void attn_mfma(
    const unsigned short* __restrict__ Qhi, const unsigned short* __restrict__ Qlo,
    const unsigned short* __restrict__ Khi, const unsigned short* __restrict__ Klo,
    const unsigned short* __restrict__ Vt, unsigned short* __restrict__ Ob, int S) {
  __shared__ unsigned short Kh_s[3 * 4096];  // per buf: 4 chunks [32 keys x 32 dims]
  __shared__ unsigned short Kl_s[3 * 4096];
  __shared__ unsigned short V_s[3 * 4096];   // per buf: [128 dims x 32 keys]
  __shared__ unsigned short P_s[4 * 640];    // per wave: [16 q x 40 keys(pad)]
  const int t = threadIdx.x;
  const int wave = t >> 6, lane = t & 63, quad = lane >> 4, l15 = lane & 15;
  const int bidall = blockIdx.x;
  const size_t boff = (size_t)(bidall >> 8) * (2048 * 2048);
  Qhi += boff; Qlo += boff; Khi += boff; Klo += boff; Vt += boff; Ob += boff;
  const int bid = bidall & 255;
  const int xcd = bid & 7, slot = bid >> 3;   // slot in [0,32)
  const int head = (xcd << 1) | (slot >> 4);  // 2 heads per XCD -> K/V in L2
  const int qblk = slot & 15;                 // 16 q-blocks of 128
  const size_t hoff = (size_t)head * 128;
  const int cq0 = (quad * 8) ^ SWZ(l15);

  bf16x8 qh[2][4], ql[2][4];
#pragma unroll
  for (int g = 0; g < 2; ++g) {
    const int qb = qblk * 128 + g * 64 + wave * 16;
#pragma unroll
    for (int kb = 0; kb < 4; ++kb) {
      size_t off = (size_t)(qb + l15) * 2048 + hoff + kb * 32 + quad * 8;
      qh[g][kb] = *(const bf16x8*)(Qhi + off);
      ql[g][kb] = *(const bf16x8*)(Qlo + off);
    }
  }
  f32x4 o[2][8] = {};   // per group: O^T[d = rb*16+quad*4+r][q = l15]
  float m_run[2] = {-INFINITY, -INFINITY}, l_run[2] = {0.f, 0.f};

  const int lr = lane >> 2, lc = DMA_COL(lane);
  const unsigned short* gKh = Khi + (size_t)lr * 2048 + hoff + wave * 32 + lc;
  const unsigned short* gKl = Klo + (size_t)lr * 2048 + hoff + wave * 32 + lc;
  const unsigned short* gV  = Vt + (hoff + wave * 32 + lr) * (size_t)S + lc;
  unsigned short* Pw = P_s + wave * 640;

  auto stage = [&](int buf, int kpos) {
    const int b4 = buf * 4096 + wave * 1024;
#pragma unroll
    for (int i = 0; i < 2; ++i) {
      ld_lds16(gKh + (size_t)(kpos + i * 16) * 2048, Kh_s + b4 + i * 512);
      ld_lds16(gKl + (size_t)(kpos + i * 16) * 2048, Kl_s + b4 + i * 512);
      ld_lds16(gV + (size_t)(i * 16) * S + kpos,      V_s + b4 + i * 512);
    }
  };
  stage(0, 0);
  stage(1, 32);
  asm volatile("s_waitcnt vmcnt(6)" ::: "memory");
  __builtin_amdgcn_s_barrier();
  __builtin_amdgcn_sched_barrier(0);

  int cur = 0, st = 2;
  for (int tix = 0; tix < 64; ++tix) {
    if (tix + 2 < 64) stage(st, (tix + 2) * 32);
    const int cb = cur * 4096;
    f32x4 s[2][2] = {};
    __builtin_amdgcn_s_setprio(1);
#pragma unroll
    for (int mb = 0; mb < 2; ++mb)
#pragma unroll
      for (int kb = 0; kb < 4; ++kb) {
        bf16x8 kh = *(bf16x8*)&Kh_s[cb + kb * 1024 + (mb * 16 + l15) * 32 + cq0];
        bf16x8 kl = *(bf16x8*)&Kl_s[cb + kb * 1024 + (mb * 16 + l15) * 32 + cq0];
        s[0][mb] = __builtin_amdgcn_mfma_f32_16x16x32_bf16(kh, qh[0][kb], s[0][mb], 0, 0, 0);
        s[0][mb] = __builtin_amdgcn_mfma_f32_16x16x32_bf16(kh, ql[0][kb], s[0][mb], 0, 0, 0);
        s[0][mb] = __builtin_amdgcn_mfma_f32_16x16x32_bf16(kl, qh[0][kb], s[0][mb], 0, 0, 0);
        s[1][mb] = __builtin_amdgcn_mfma_f32_16x16x32_bf16(kh, qh[1][kb], s[1][mb], 0, 0, 0);
        s[1][mb] = __builtin_amdgcn_mfma_f32_16x16x32_bf16(kh, ql[1][kb], s[1][mb], 0, 0, 0);
        s[1][mb] = __builtin_amdgcn_mfma_f32_16x16x32_bf16(kl, qh[1][kb], s[1][mb], 0, 0, 0);
      }
    __builtin_amdgcn_s_setprio(0);

    bf16x8 pf[2];
#pragma unroll
    for (int g = 0; g < 2; ++g) {
      float mt = s[g][0][0];
#pragma unroll
      for (int r = 1; r < 4; ++r) mt = fmaxf(mt, s[g][0][r]);
#pragma unroll
      for (int r = 0; r < 4; ++r) mt = fmaxf(mt, s[g][1][r]);
      mt = fmaxf(mt, __shfl_xor(mt, 16));
      mt = fmaxf(mt, __shfl_xor(mt, 32));
      // defer-max: rescale only when some query's max grew by > 8 (base-2)
      if (!__all(mt <= m_run[g] + 8.f)) {
        const float m_new = fmaxf(m_run[g], mt);
        const float alpha = __builtin_amdgcn_exp2f(m_run[g] - m_new);
        l_run[g] *= alpha;
#pragma unroll
        for (int rb = 0; rb < 8; ++rb)
#pragma unroll
          for (int r = 0; r < 4; ++r) o[g][rb][r] *= alpha;
        m_run[g] = m_new;
      }
      float p[8];
#pragma unroll
      for (int mb = 0; mb < 2; ++mb)
#pragma unroll
        for (int r = 0; r < 4; ++r)
          p[mb * 4 + r] = __builtin_amdgcn_exp2f(s[g][mb][r] - m_run[g]);
      float rs = p[0];
#pragma unroll
      for (int j = 1; j < 8; ++j) rs += p[j];
      rs += __shfl_xor(rs, 16);
      rs += __shfl_xor(rs, 32);
      l_run[g] += rs;
#pragma unroll
      for (int mb = 0; mb < 2; ++mb) {
        ushort4 pk;
        pk.x = f2bf(p[mb * 4 + 0]);
        pk.y = f2bf(p[mb * 4 + 1]);
        pk.z = f2bf(p[mb * 4 + 2]);
        pk.w = f2bf(p[mb * 4 + 3]);
        *(ushort4*)&Pw[l15 * 40 + mb * 16 + quad * 4] = pk;
      }
      pf[g] = *(bf16x8*)&Pw[l15 * 40 + quad * 8];  // same-wave DS in-order
    }
    __builtin_amdgcn_s_setprio(1);
#pragma unroll
    for (int rb = 0; rb < 8; ++rb) {
      bf16x8 vb = *(bf16x8*)&V_s[cb + (rb * 16 + l15) * 32 + cq0];
      o[0][rb] = __builtin_amdgcn_mfma_f32_16x16x32_bf16(vb, pf[0], o[0][rb], 0, 0, 0);
      o[1][rb] = __builtin_amdgcn_mfma_f32_16x16x32_bf16(vb, pf[1], o[1][rb], 0, 0, 0);
    }
    __builtin_amdgcn_s_setprio(0);
    if (tix + 2 < 64) asm volatile("s_waitcnt vmcnt(6)" ::: "memory");
    else              asm volatile("s_waitcnt vmcnt(0)" ::: "memory");
    __builtin_amdgcn_s_barrier();
    __builtin_amdgcn_sched_barrier(0);
    cur = cur == 2 ? 0 : cur + 1;
    st = st == 2 ? 0 : st + 1;
  }
#pragma unroll
  for (int g = 0; g < 2; ++g) {
    const int qb = qblk * 128 + g * 64 + wave * 16;
    const float inv = 1.0f / l_run[g];
#pragma unroll
    for (int rb = 0; rb < 8; ++rb) {
      ushort4 pk;
      pk.x = f2bf(o[g][rb][0] * inv);
      pk.y = f2bf(o[g][rb][1] * inv);
      pk.z = f2bf(o[g][rb][2] * inv);
      pk.w = f2bf(o[g][rb][3] * inv);
      *(ushort4*)(Ob + (size_t)(qb + l15) * 2048 + hoff + rb * 16 + quad * 4) = pk;
    }
  }
}

extern "C" void kernel_launch(void* const* d_in, const int* in_sizes, int n_in,
                              void* d_out, int out_size, void* d_ws, size_t ws_size,
                              hipStream_t stream) {
  (void)in_sizes; (void)n_in; (void)out_size;
  const float* X   = (const float*)d_in[0];
  const float* W_Q = (const float*)d_in[2];
  const float* W_K = (const float*)d_in[3];
  const float* W_V = (const float*)d_in[4];
  const float* W_O = (const float*)d_in[5];
  float* out = (float*)d_out;

  const int S = 2048, HD = 2048;
  const size_t P = (size_t)HD * HD;
  unsigned short* w = (unsigned short*)d_ws;
  unsigned short* WqThi = w;
  unsigned short* WqTlo = w + P;
  unsigned short* WkThi = w + 2 * P;
  unsigned short* WkTlo = w + 3 * P;
  unsigned short* WvThi = w + 4 * P;
  unsigned short* WoThi = w + 5 * P;   // 128 x 2048 (N x K)
  unsigned short* base6 = w + 5 * P + P / 16;

  // log2(e)/sqrt(128) folded into Q at projection time (base-2 softmax)
  const float qscale = 0.12752551286084109f;

  dim3 bT(32, 8);
  tsplit<true ><<<dim3(64, 64), bT, 0, stream>>>(W_Q, WqThi, WqTlo, HD, HD);
  tsplit<true ><<<dim3(64, 64), bT, 0, stream>>>(W_K, WkThi, WkTlo, HD, HD);
  tsplit<false><<<dim3(64, 64), bT, 0, stream>>>(W_V, WvThi, nullptr, HD, HD);
  tsplit<false><<<dim3(4, 64),  bT, 0, stream>>>(W_O, WoThi, nullptr, HD, 128);

  // tiers: chunk of C batches needs (5P + P/16 + 7*C*P) elements * 2 bytes
  const size_t elW = 5 * P + P / 16;
  const size_t need2 = (elW + 14 * P) * 2;   // ~160 MB
  const size_t need1 = (elW + 7 * P) * 2;    // ~101 MB
  int C; bool tight = false;
  if (ws_size >= need2)      C = 2;
  else if (ws_size >= need1) C = 1;
  else { C = 1; tight = true; }              // tight layout (Vt=Xlo)

  const size_t CP = (size_t)C * P;
  unsigned short* Xhi = base6;
  unsigned short* Xlo = base6 + CP;
  unsigned short* Qhi = base6 + 2 * CP;
  unsigned short* Qlo = base6 + 3 * CP;
  unsigned short* Khi = base6 + 4 * CP;
  unsigned short* Klo = base6 + 5 * CP;
  unsigned short* Vt  = tight ? Xlo : base6 + 6 * CP;
  unsigned short* attnB = Xhi;            // alias: X dead after QKV
  float* fpart = (float*)Qhi;             // alias: Q/K dead after attn (4CP span)

  const int M = C * S;                    // chunk rows
  const int zn = 16 / C;                  // gemm_out K-slices -> 256 blocks
  const int ldk = HD / zn;
  const int NOUT = M * 128;

  for (int c = 0; c < 4 / C; ++c) {
    split_f32<<<C * 4096, 256, 0, stream>>>(X + (size_t)c * CP, Xhi, Xlo, (int)CP);
    gemm_qkv3<<<dim3(16, C * 8, 2), 512, 0, stream>>>(
        Xhi, Xlo, WqThi, WqTlo, WkThi, WkTlo, WvThi,
        Qhi, Qlo, Khi, Klo, Vt, qscale);
    attn_mfma<<<C * 256, 256, 0, stream>>>(Qhi, Qlo, Khi, Klo, Vt, attnB, S);
    gemm_out<<<dim3(1, C * 16, zn), 256, 0, stream>>>(attnB, WoThi, fpart, M, 128, HD, ldk);
    reduceN<<<NOUT / 1024, 256, 0, stream>>>(fpart, out + (size_t)c * NOUT, NOUT, zn);
  }
}